// Round 4
// baseline (576.308 us; speedup 1.0000x reference)
//
#include <hip/hip_runtime.h>
#include <math.h>

#define NT      32768
#define DIM     2048
#define NE      64
#define RSCALE  2.5f
#define REPS    1e-20f
#define BK      64
#define TOK     64
#define NCHUNK  (DIM / BK)

typedef const __attribute__((address_space(1))) void GV;
typedef __attribute__((address_space(3))) void LV;

#define FMA4(S, HV, WV) \
    S = fmaf((HV).x, (WV).x, S); \
    S = fmaf((HV).y, (WV).y, S); \
    S = fmaf((HV).z, (WV).z, S); \
    S = fmaf((HV).w, (WV).w, S);

// 512 blocks x 512 threads (8 waves). Block = 64 tokens, wave w = experts w*8..w*8+7,
// lane = token. H double-buffered in LDS via global_load_lds (XOR-pre-swizzled source).
// W via per-lane VMEM loads (broadcast same-address, opaque-VGPR-forced so the compiler
// cannot scalarize to s_load -- s_load is OOO and forces lgkmcnt(0), draining ds_reads).
__global__ __launch_bounds__(512, 4) void router_kernel(
    const float* __restrict__ H,
    const float* __restrict__ W,
    const float* __restrict__ B,
    float* __restrict__ out)
{
    __shared__ __align__(16) float Hs[2][TOK * BK];  // 2 x 16 KB, swizzled slots
    __shared__ float Sc[TOK][NE + 1];                // scores, padded pitch
    __shared__ float Bs[NE];

    const int tid  = threadIdx.x;
    const int lane = tid & 63;
    const int wave = __builtin_amdgcn_readfirstlane(tid >> 6);
    const size_t tb = (size_t)blockIdx.x * TOK;

    if (tid < NE) Bs[tid] = B[tid];

    // opaque per-lane zero: makes W addresses non-provably-uniform -> VMEM, not SMEM.
    int vzero;
    asm volatile("v_mov_b32 %0, 0" : "=v"(vzero));

    // staging: wave stages rows wave*8 .. wave*8+7 in 2 rounds of 4 rows.
    // LDS dest linear (base + lane*16B): lane -> (row = base + lane>>4, slot_phys = lane&15).
    // Content: Hs[row][slot] = H_row[k0 + 4*(slot ^ (row&7)) ..] -> pre-swizzle global source.
    const int sp    = lane & 15;
    const int srow0 = wave * 8 + (lane >> 4);
    const int srow1 = srow0 + 4;
    const float* g0 = H + (tb + (size_t)srow0) * DIM + ((sp ^ (srow0 & 7)) << 2);
    const float* g1 = H + (tb + (size_t)srow1) * DIM + ((sp ^ (srow1 & 7)) << 2);
    const int lo0 = (wave * 8) * BK;
    const int lo1 = (wave * 8 + 4) * BK;

    const int we = wave * 8;                         // expert base
    const float* wbase = W + (size_t)we * DIM + vzero;   // per-lane (broadcast) base

    float  c[8];
    double acc[8];
    #pragma unroll
    for (int j = 0; j < 8; ++j) { c[j] = 0.0f; acc[j] = 0.0; }

    // prologue: stage chunk 0 into buffer 0
    __builtin_amdgcn_global_load_lds((GV*)g0, (LV*)&Hs[0][lo0], 16, 0, 0);
    __builtin_amdgcn_global_load_lds((GV*)g1, (LV*)&Hs[0][lo1], 16, 0, 0);
    __syncthreads();

    for (int ch = 0; ch < NCHUNK; ++ch) {
        const int cur = ch & 1;
        const int k0  = ch * BK;

        // stage NEXT chunk first -- latency hides under this chunk's compute
        if (ch + 1 < NCHUNK) {
            const int kn = k0 + BK;
            __builtin_amdgcn_global_load_lds((GV*)(g0 + kn), (LV*)&Hs[cur ^ 1][lo0], 16, 0, 0);
            __builtin_amdgcn_global_load_lds((GV*)(g1 + kn), (LV*)&Hs[cur ^ 1][lo1], 16, 0, 0);
        }

        const float* hrow = &Hs[cur][lane * BK];
        #pragma unroll
        for (int k16 = 0; k16 < 4; ++k16) {
            float4 hv[4];
            #pragma unroll
            for (int i = 0; i < 4; ++i) {
                const int s = k16 * 4 + i;
                hv[i] = *(const float4*)&hrow[(s ^ (lane & 7)) << 2];
            }
            #pragma unroll
            for (int k4 = 0; k4 < 4; ++k4) {
                float4 wv[8];
                #pragma unroll
                for (int e = 0; e < 8; ++e)
                    wv[e] = *(const float4*)(wbase + (size_t)e * DIM + k0 + k16 * 16 + k4 * 4);
                #pragma unroll
                for (int e = 0; e < 8; ++e) {
                    float s0 = c[e];
                    FMA4(s0, hv[k4], wv[e]);
                    c[e] = s0;
                }
            }
            // flush 16-dim fp32 subchunk into fp64 master (rank-exactness vs np reference)
            #pragma unroll
            for (int j = 0; j < 8; ++j) { acc[j] += (double)c[j]; c[j] = 0.0f; }
        }
        __syncthreads();   // next buffer staged; cur free for overwrite
    }

    // sigmoid scores into LDS: token = lane, experts we..we+7
    #pragma unroll
    for (int j = 0; j < 8; ++j) {
        float logit = (float)acc[j];
        Sc[lane][we + j] = 1.0f / (1.0f + expf(-logit));
    }
    __syncthreads();

    // grouped top-k, one token per active thread, spread across all 8 waves
    if ((tid & 7) == 0) {
        const int t = tid >> 3;                    // 0..63
        const float* sc = Sc[t];
        float gs[8];
        #pragma unroll
        for (int g = 0; g < 8; ++g) {
            float m1 = -1e30f, m2 = -1e30f;
            #pragma unroll
            for (int j = 0; j < 8; ++j) {
                float v = sc[g * 8 + j] + Bs[g * 8 + j];
                if (v > m1) { m2 = m1; m1 = v; }
                else if (v > m2) { m2 = v; }
            }
            gs[g] = m1 + m2;
        }
        unsigned gmask = 0;
        for (int i = 0; i < 4; ++i) {
            float best = -1e30f; int bg = 0;
            for (int g = 0; g < 8; ++g)
                if (!((gmask >> g) & 1u) && gs[g] > best) { best = gs[g]; bg = g; }
            gmask |= 1u << bg;
        }
        unsigned long long picked = 0ull;
        int   idxs[8];
        float wts[8];
        float wsum = 0.0f;
        for (int i = 0; i < 8; ++i) {
            float best = -1e30f; int bi = 0;
            for (int e = 0; e < 64; ++e) {
                if ((picked >> e) & 1ull) continue;
                float v = ((gmask >> (e >> 3)) & 1u) ? (sc[e] + Bs[e]) : 0.0f;
                if (v > best) { best = v; bi = e; }
            }
            picked |= 1ull << bi;
            idxs[i] = bi;
            wts[i] = sc[bi];
            wsum += sc[bi];
        }
        const float scale = RSCALE / (wsum + REPS);
        const size_t token = tb + t;
        #pragma unroll
        for (int i = 0; i < 8; ++i) {
            out[token * 8 + i] = (float)idxs[i];
            out[(size_t)NT * 8 + token * 8 + i] = wts[i] * scale;
        }
    }
}

extern "C" void kernel_launch(void* const* d_in, const int* in_sizes, int n_in,
                              void* d_out, int out_size, void* d_ws, size_t ws_size,
                              hipStream_t stream) {
    (void)in_sizes; (void)n_in; (void)out_size; (void)d_ws; (void)ws_size;
    const float* H = (const float*)d_in[0];
    const float* W = (const float*)d_in[1];
    const float* B = (const float*)d_in[2];
    float* out = (float*)d_out;
    router_kernel<<<dim3(NT / TOK), dim3(512), 0, stream>>>(H, W, B, out);
}

// Round 5
// 137.686 us; speedup vs baseline: 4.1857x; 4.1857x over previous
//
#include <hip/hip_runtime.h>
#include <math.h>

#define NT 32768
#define DIM 2048
#define NE 64
#define RSCALE 2.5f
#define REPS 1e-20f
#define KC 32
#define NCH (DIM / KC)
#define TOK 64

typedef const __attribute__((address_space(1))) void GV;
typedef __attribute__((address_space(3))) void LV;
typedef __attribute__((ext_vector_type(8))) short short8x;
typedef __attribute__((ext_vector_type(4))) float f32x4;
typedef __attribute__((ext_vector_type(4))) unsigned int uint4x;
typedef __attribute__((ext_vector_type(2))) unsigned int uint2x;

// LDS arena (bytes):
//   Hs[2][64*32] f32   : 0     .. 16384   (double-buffered H chunk, swizzled 16B slots)
//   WL[2][3][64*40] s16: 16384 .. 47104   (double-buffered W limb chunks, pitch 40 sh = 80 B)
//   Bs[64] f32         : 47104 .. 47360
//   Sc[64][65] f32     : alias at 0 (used after main loop only)
#define HS_FLOATS 2048
#define WL_OFF 16384
#define WL_PITCH 40
#define WL_LIMB (64 * WL_PITCH)
#define WL_BUF (3 * WL_LIMB)
#define BS_OFF 47104
#define ARENA_BYTES 47424

// truncation split: hi16 of two fp32 packed into one dword (low = even element)
#define PACKHI(odd, even) __builtin_amdgcn_perm((odd), (even), 0x07060302u)

__device__ __forceinline__ void decomp4(f32x4 x, unsigned int o[6]) {
    unsigned int u0 = __float_as_uint(x.x), u1 = __float_as_uint(x.y);
    unsigned int u2 = __float_as_uint(x.z), u3 = __float_as_uint(x.w);
    o[0] = PACKHI(u1, u0); o[1] = PACKHI(u3, u2);
    float r0 = x.x - __uint_as_float(u0 & 0xffff0000u);
    float r1 = x.y - __uint_as_float(u1 & 0xffff0000u);
    float r2 = x.z - __uint_as_float(u2 & 0xffff0000u);
    float r3 = x.w - __uint_as_float(u3 & 0xffff0000u);
    unsigned int v0 = __float_as_uint(r0), v1 = __float_as_uint(r1);
    unsigned int v2 = __float_as_uint(r2), v3 = __float_as_uint(r3);
    o[2] = PACKHI(v1, v0); o[3] = PACKHI(v3, v2);
    float s0 = r0 - __uint_as_float(v0 & 0xffff0000u);
    float s1 = r1 - __uint_as_float(v1 & 0xffff0000u);
    float s2 = r2 - __uint_as_float(v2 & 0xffff0000u);
    float s3 = r3 - __uint_as_float(v3 & 0xffff0000u);
    o[4] = PACKHI(__float_as_uint(s1), __float_as_uint(s0));
    o[5] = PACKHI(__float_as_uint(s3), __float_as_uint(s2));
}

__device__ __forceinline__ void decomp8(f32x4 a, f32x4 b,
                                        short8x* f0, short8x* f1, short8x* f2) {
    unsigned int oa[6], ob[6];
    decomp4(a, oa); decomp4(b, ob);
    uint4x t0 = {oa[0], oa[1], ob[0], ob[1]};
    uint4x t1 = {oa[2], oa[3], ob[2], ob[3]};
    uint4x t2 = {oa[4], oa[5], ob[4], ob[5]};
    *f0 = __builtin_bit_cast(short8x, t0);
    *f1 = __builtin_bit_cast(short8x, t1);
    *f2 = __builtin_bit_cast(short8x, t2);
}

// 512 blocks x 256 threads (4 waves). Block = 64 tokens x 64 experts, K=2048.
// Wave w: tokens (w&1)*32, experts (w>>1)*32 -> 4 MFMA tiles 16x16, mfma_f32_16x16x32_bf16.
// fp32 emulated via 3-limb bf16 truncation split, 6 limb-product MFMAs; main term in its
// own accumulator; fp64 master drain every 8 chunks (K=256) for rank-exact logits.
__global__ __launch_bounds__(256) void router_kernel(
    const float* __restrict__ H,
    const float* __restrict__ W,
    const float* __restrict__ B,
    float* __restrict__ out)
{
    __shared__ __align__(16) char arena[ARENA_BYTES];
    float* hsf = (float*)(arena);
    short* wl  = (short*)(arena + WL_OFF);
    float* bsf = (float*)(arena + BS_OFF);
    float* scf = (float*)(arena);        // epilogue alias over Hs

    const int tid  = threadIdx.x;
    const int lane = tid & 63;
    const int w    = tid >> 6;
    const size_t tb = (size_t)blockIdx.x * TOK;

    if (tid < NE) bsf[tid] = B[tid];

    const int l15 = lane & 15, g = lane >> 4, l7 = lane & 7;
    const int tg = (w & 1) * 32, eg = (w >> 1) * 32;

    // H staging: wave w stages rows w*16..w*16+15, 2 rounds of 8 rows; linear LDS dest,
    // pre-swizzled global source (content: Hs[row][slot] = H[row][4*(slot ^ (row&7))..])
    const int sp = lane & 7, ro = lane >> 3;
    const float* hg0 = H + (tb + (size_t)(w * 16 + ro)) * DIM + ((sp ^ ro) << 2);
    const float* hg1 = H + (tb + (size_t)(w * 16 + 8 + ro)) * DIM + ((sp ^ ro) << 2);
    const int hb0 = (w * 16) * KC * 4;          // byte offset within H buffer
    const int hb1 = (w * 16 + 8) * KC * 4;

    // W staging: thread handles (e, q) and (e+32, q): 4 fp32 each -> 3 limbs x 8B writes
    const int we0 = tid >> 3, wq0 = tid & 7;

    f32x4 Cm[2][2], Cc[2][2];
    double md[2][2][4];
    #pragma unroll
    for (int a = 0; a < 2; ++a)
        #pragma unroll
        for (int b = 0; b < 2; ++b) {
            Cm[a][b] = (f32x4)0.0f; Cc[a][b] = (f32x4)0.0f;
            #pragma unroll
            for (int r = 0; r < 4; ++r) md[a][b][r] = 0.0;
        }

    // ---- prologue: stage chunk 0 into buffer 0
    {
        __builtin_amdgcn_global_load_lds((GV*)hg0, (LV*)(arena + hb0), 16, 0, 0);
        __builtin_amdgcn_global_load_lds((GV*)hg1, (LV*)(arena + hb1), 16, 0, 0);
        f32x4 wv0 = *(const f32x4*)&W[(size_t)we0 * DIM + wq0 * 4];
        f32x4 wv1 = *(const f32x4*)&W[(size_t)(we0 + 32) * DIM + wq0 * 4];
        unsigned int o[6];
        decomp4(wv0, o);
        #pragma unroll
        for (int L = 0; L < 3; ++L)
            *(uint2x*)&wl[L * WL_LIMB + we0 * WL_PITCH + wq0 * 4] =
                (uint2x){o[2 * L], o[2 * L + 1]};
        decomp4(wv1, o);
        #pragma unroll
        for (int L = 0; L < 3; ++L)
            *(uint2x*)&wl[L * WL_LIMB + (we0 + 32) * WL_PITCH + wq0 * 4] =
                (uint2x){o[2 * L], o[2 * L + 1]};
    }
    __syncthreads();

    for (int ch = 0; ch < NCH; ++ch) {
        const int p = ch & 1;
        const bool pre = (ch + 1) < NCH;

        // issue next chunk's loads early (latency hides under compute)
        f32x4 wv0, wv1;
        if (pre) {
            const int kn = (ch + 1) * KC;
            __builtin_amdgcn_global_load_lds((GV*)(hg0 + kn),
                (LV*)(arena + (p ^ 1) * HS_FLOATS * 4 + hb0), 16, 0, 0);
            __builtin_amdgcn_global_load_lds((GV*)(hg1 + kn),
                (LV*)(arena + (p ^ 1) * HS_FLOATS * 4 + hb1), 16, 0, 0);
            wv0 = *(const f32x4*)&W[(size_t)we0 * DIM + kn + wq0 * 4];
            wv1 = *(const f32x4*)&W[(size_t)(we0 + 32) * DIM + kn + wq0 * 4];
        }

        // A fragments: 2 token-tiles x 3 limbs
        short8x af[2][3];
        #pragma unroll
        for (int tt = 0; tt < 2; ++tt) {
            const int t = tg + tt * 16 + l15;
            const float* hr = &hsf[p * HS_FLOATS + t * KC];
            f32x4 xa = *(const f32x4*)&hr[((g * 2) ^ l7) << 2];
            f32x4 xb = *(const f32x4*)&hr[((g * 2 + 1) ^ l7) << 2];
            decomp8(xa, xb, &af[tt][0], &af[tt][1], &af[tt][2]);
        }

        // B fragments + MFMAs: per expert-tile read 3 limb frags, 12 MFMAs
        const short* wlp = &wl[p * WL_BUF];
        #pragma unroll
        for (int et = 0; et < 2; ++et) {
            const int e = eg + et * 16 + l15;
            short8x b0 = *(const short8x*)&wlp[0 * WL_LIMB + e * WL_PITCH + g * 8];
            short8x b1 = *(const short8x*)&wlp[1 * WL_LIMB + e * WL_PITCH + g * 8];
            short8x b2 = *(const short8x*)&wlp[2 * WL_LIMB + e * WL_PITCH + g * 8];
            #pragma unroll
            for (int tt = 0; tt < 2; ++tt) {
                Cm[tt][et] = __builtin_amdgcn_mfma_f32_16x16x32_bf16(af[tt][0], b0, Cm[tt][et], 0, 0, 0);
                Cc[tt][et] = __builtin_amdgcn_mfma_f32_16x16x32_bf16(af[tt][1], b0, Cc[tt][et], 0, 0, 0);
                Cc[tt][et] = __builtin_amdgcn_mfma_f32_16x16x32_bf16(af[tt][2], b0, Cc[tt][et], 0, 0, 0);
                Cc[tt][et] = __builtin_amdgcn_mfma_f32_16x16x32_bf16(af[tt][0], b1, Cc[tt][et], 0, 0, 0);
                Cc[tt][et] = __builtin_amdgcn_mfma_f32_16x16x32_bf16(af[tt][1], b1, Cc[tt][et], 0, 0, 0);
                Cc[tt][et] = __builtin_amdgcn_mfma_f32_16x16x32_bf16(af[tt][0], b2, Cc[tt][et], 0, 0, 0);
            }
        }

        // W decompose + LDS writes for next chunk (loads landed under the MFMAs)
        if (pre) {
            short* wn = &wl[(p ^ 1) * WL_BUF];
            unsigned int o[6];
            decomp4(wv0, o);
            #pragma unroll
            for (int L = 0; L < 3; ++L)
                *(uint2x*)&wn[L * WL_LIMB + we0 * WL_PITCH + wq0 * 4] =
                    (uint2x){o[2 * L], o[2 * L + 1]};
            decomp4(wv1, o);
            #pragma unroll
            for (int L = 0; L < 3; ++L)
                *(uint2x*)&wn[L * WL_LIMB + (we0 + 32) * WL_PITCH + wq0 * 4] =
                    (uint2x){o[2 * L], o[2 * L + 1]};
        }

        // fp64 master drain every 8 chunks (K=256)
        if ((ch & 7) == 7) {
            #pragma unroll
            for (int tt = 0; tt < 2; ++tt)
                #pragma unroll
                for (int et = 0; et < 2; ++et) {
                    #pragma unroll
                    for (int r = 0; r < 4; ++r)
                        md[tt][et][r] += (double)Cm[tt][et][r] + (double)Cc[tt][et][r];
                    Cm[tt][et] = (f32x4)0.0f;
                    Cc[tt][et] = (f32x4)0.0f;
                }
        }
        __syncthreads();
    }

    // sigmoid scores -> Sc (aliases dead Hs/WL space)
    #pragma unroll
    for (int tt = 0; tt < 2; ++tt)
        #pragma unroll
        for (int et = 0; et < 2; ++et)
            #pragma unroll
            for (int r = 0; r < 4; ++r) {
                float logit = (float)md[tt][et][r];
                float s = 1.0f / (1.0f + expf(-logit));
                int t = tg + tt * 16 + g * 4 + r;
                int e = eg + et * 16 + l15;
                scf[t * 65 + e] = s;
            }
    __syncthreads();

    // grouped top-k, one token per active thread (spread over all 4 waves)
    if ((tid & 3) == 0) {
        const int t = tid >> 2;
        const float* sc = &scf[t * 65];
        float gs[8];
        #pragma unroll
        for (int gg = 0; gg < 8; ++gg) {
            float m1 = -1e30f, m2 = -1e30f;
            #pragma unroll
            for (int j = 0; j < 8; ++j) {
                float v = sc[gg * 8 + j] + bsf[gg * 8 + j];
                if (v > m1) { m2 = m1; m1 = v; }
                else if (v > m2) { m2 = v; }
            }
            gs[gg] = m1 + m2;
        }
        unsigned gmask = 0;
        for (int i = 0; i < 4; ++i) {
            float best = -1e30f; int bg = 0;
            for (int gg = 0; gg < 8; ++gg)
                if (!((gmask >> gg) & 1u) && gs[gg] > best) { best = gs[gg]; bg = gg; }
            gmask |= 1u << bg;
        }
        unsigned long long picked = 0ull;
        int   idxs[8];
        float wts[8];
        float wsum = 0.0f;
        for (int i = 0; i < 8; ++i) {
            float best = -1e30f; int bi = 0;
            for (int e = 0; e < 64; ++e) {
                if ((picked >> e) & 1ull) continue;
                float v = ((gmask >> (e >> 3)) & 1u) ? (sc[e] + bsf[e]) : 0.0f;
                if (v > best) { best = v; bi = e; }
            }
            picked |= 1ull << bi;
            idxs[i] = bi;
            wts[i] = sc[bi];
            wsum += sc[bi];
        }
        const float scale = RSCALE / (wsum + REPS);
        const size_t token = tb + t;
        #pragma unroll
        for (int i = 0; i < 8; ++i) {
            out[token * 8 + i] = (float)idxs[i];
            out[(size_t)NT * 8 + token * 8 + i] = wts[i] * scale;
        }
    }
}

extern "C" void kernel_launch(void* const* d_in, const int* in_sizes, int n_in,
                              void* d_out, int out_size, void* d_ws, size_t ws_size,
                              hipStream_t stream) {
    (void)in_sizes; (void)n_in; (void)out_size; (void)d_ws; (void)ws_size;
    const float* H = (const float*)d_in[0];
    const float* W = (const float*)d_in[1];
    const float* B = (const float*)d_in[2];
    float* out = (float*)d_out;
    router_kernel<<<dim3(NT / TOK), dim3(256), 0, stream>>>(H, W, B, out);
}